// Round 11
// baseline (32.471 us; speedup 1.0000x reference)
//
#include <hip/hip_runtime.h>

// EmbeddingBag(mean): B=1024, S=256, W=16, EMB=50, vocab=256.
// Round 11: descending length-sort + GROUP-OF-4 flat gather + r6 pipeline.
//  - Theory: r6's 16-level if(len>k) tree = 16 serial exec-mask epochs/pass
//    (saveexec+cbranch gating each ds_read). Group-of-4 = max 4 epochs with
//    4 independent ds_read_b128 each (4-deep DS ILP). Sort makes group
//    count wave-uniform (~2.65 avg vs wave-max); masked lanes in a partial
//    group hit the sentinel row at the SAME address -> LDS broadcast, ~free.
//  - Direct A/B vs r7: identical sort/prefetch/store framework, only the
//    gather body changes (16-level tree -> 4 groups of 4 predicated reads).
//  - Keeps: order[] in LDS so next pass's chars prefetch issues before the
//    current gather; descending order puts the ragged 44-bag tail on the
//    shortest bags; 13 lanes/bag; 56-dword fp32 rows; sentinel row 256.

constexpr int EMB     = 50;
constexpr int RSTRIDE = 56;                  // dwords per padded row (224 B)
constexpr int ROWS    = 257;                 // 256 vocab + zero sentinel
constexpr int TBL_F   = ROWS * RSTRIDE;      // 14392 floats
constexpr int NBAGS   = 1024 * 256;          // 262144
constexpr int BLOCK   = 1024;
constexpr int TPB     = 13;                  // lanes per bag
constexpr int BPP     = BLOCK / TPB;         // 78 bags per pass
constexpr int CHUNK   = 512;                 // bags per block
constexpr int NPASS   = (CHUNK + BPP - 1) / BPP;  // 7 (tail: 44 shortest bags)
constexpr int BLOCKS  = NBAGS / CHUNK;       // 512, exact

__global__ __launch_bounds__(BLOCK, 8) void embag_sortg4_kernel(
    const int*   __restrict__ chars,     // [NBAGS, W=16]
    const int*   __restrict__ lengths,   // [NBAGS]
    const float* __restrict__ table,     // [256, EMB]
    float*       __restrict__ out)       // [NBAGS, EMB]
{
    __shared__ float          tbl[TBL_F];
    __shared__ unsigned short order[CHUNK];   // (len<<9) | local_bag_id
    __shared__ unsigned       bins[17];
    __shared__ float          invl[17];

    const int base = blockIdx.x * CHUNK;

    if (threadIdx.x < 17) {
        bins[threadIdx.x] = 0;
        invl[threadIdx.x] = threadIdx.x ? 1.0f / (float)threadIdx.x : 0.0f;
    }
    // Stage table (row 256 and cols 50..55 zero).
    for (int i = threadIdx.x; i < TBL_F; i += BLOCK) {
        const int r = i / RSTRIDE;
        const int c = i - r * RSTRIDE;
        tbl[i] = (r < 256 && c < EMB) ? table[r * EMB + c] : 0.0f;
    }
    __syncthreads();

    int myLen = 0, myTicket = 0;
    if (threadIdx.x < CHUNK) {
        myLen = lengths[base + threadIdx.x];              // in [1,16]
        myTicket = (int)atomicAdd(&bins[myLen], 1u);
    }
    __syncthreads();
    if (threadIdx.x == 0) {       // descending start offsets: len=16 first
        unsigned s = 0;
        for (int l = 16; l >= 1; --l) { unsigned c = bins[l]; bins[l] = s; s += c; }
    }
    __syncthreads();
    if (threadIdx.x < CHUNK)
        order[bins[myLen] + myTicket] =
            (unsigned short)((myLen << 9) | threadIdx.x);
    __syncthreads();

    const int  lb     = threadIdx.x / TPB;             // bag slot in pass
    const int  t      = threadIdx.x - lb * TPB;        // 16B slot in row
    const bool active = (lb < BPP);
    const float* rowp = tbl + 4 * t;

    // Prologue: read slot-0 order + prefetch its chars.
    int oi = active ? lb : 0;
    unsigned ord = order[oi];
    const int4* cp0 = reinterpret_cast<const int4*>(
        chars + (size_t)(base + (int)(ord & 511u)) * 16);
    int4 c0 = cp0[0], c1 = cp0[1], c2 = cp0[2], c3 = cp0[3];

    for (int p = 0; p < NPASS; ++p) {
        // Prefetch next pass (order[] already in LDS -> loads issue now,
        // retire under the gathers below).
        const int oin = (oi + BPP < CHUNK) ? oi + BPP : CHUNK - 1;
        const unsigned ordn = order[oin];
        const int4* cpn = reinterpret_cast<const int4*>(
            chars + (size_t)(base + (int)(ordn & 511u)) * 16);
        const int4 n0 = cpn[0], n1 = cpn[1], n2 = cpn[2], n3 = cpn[3];

        if (active && oi < CHUNK) {
            const int len = (int)(ord >> 9);
            const int bag = base + (int)(ord & 511u);

            float4 s0 = make_float4(0.f,0.f,0.f,0.f);
            float4 s1 = s0, s2 = s0, s3 = s0;

            // One group: 4 predicated independent ds_read_b128 + adds.
            // Masked lanes read sentinel row 256 (same addr -> broadcast).
            #define G4(c, wb)                                                  \
                {                                                              \
                    const int e0 = ((wb)+0 < len) ? (c).x : 256;               \
                    const int e1 = ((wb)+1 < len) ? (c).y : 256;               \
                    const int e2 = ((wb)+2 < len) ? (c).z : 256;               \
                    const int e3 = ((wb)+3 < len) ? (c).w : 256;               \
                    const float4 v0 = *reinterpret_cast<const float4*>(rowp + e0 * RSTRIDE); \
                    const float4 v1 = *reinterpret_cast<const float4*>(rowp + e1 * RSTRIDE); \
                    const float4 v2 = *reinterpret_cast<const float4*>(rowp + e2 * RSTRIDE); \
                    const float4 v3 = *reinterpret_cast<const float4*>(rowp + e3 * RSTRIDE); \
                    s0.x += v0.x; s0.y += v0.y; s0.z += v0.z; s0.w += v0.w;    \
                    s1.x += v1.x; s1.y += v1.y; s1.z += v1.z; s1.w += v1.w;    \
                    s2.x += v2.x; s2.y += v2.y; s2.z += v2.z; s2.w += v2.w;    \
                    s3.x += v3.x; s3.y += v3.y; s3.z += v3.z; s3.w += v3.w;    \
                }

            G4(c0, 0)
            if (len > 4) {
                G4(c1, 4)
                if (len > 8) {
                    G4(c2, 8)
                    if (len > 12) {
                        G4(c3, 12)
                    }
                }
            }
            #undef G4

            const float inv = invl[len];
            const float rx = ((s0.x + s1.x) + (s2.x + s3.x)) * inv;
            const float ry = ((s0.y + s1.y) + (s2.y + s3.y)) * inv;
            const float rz = ((s0.z + s1.z) + (s2.z + s3.z)) * inv;
            const float rw = ((s0.w + s1.w) + (s2.w + s3.w)) * inv;

            float* ob = out + (size_t)bag * EMB + 4u * (unsigned)t;
            reinterpret_cast<float2*>(ob)[0] = make_float2(rx, ry);
            if (t < 12)
                reinterpret_cast<float2*>(ob)[1] = make_float2(rz, rw);
        }

        ord = ordn;
        c0 = n0; c1 = n1; c2 = n2; c3 = n3;
        oi += BPP;
    }
}

extern "C" void kernel_launch(void* const* d_in, const int* in_sizes, int n_in,
                              void* d_out, int out_size, void* d_ws, size_t ws_size,
                              hipStream_t stream) {
    const int*   chars   = (const int*)d_in[0];   // [B,S,W] int32
    const int*   lengths = (const int*)d_in[1];   // [B,S]   int32
    const float* table   = (const float*)d_in[2]; // [256,50] f32
    float*       out     = (float*)d_out;         // [B,S,50] f32

    embag_sortg4_kernel<<<dim3(BLOCKS), dim3(BLOCK), 0, stream>>>(
        chars, lengths, table, out);
}

// Round 12
// 24.543 us; speedup vs baseline: 1.3230x; 1.3230x over previous
//
#include <hip/hip_runtime.h>

// EmbeddingBag(mean): B=1024, S=256, W=16, EMB=50, vocab=256.
// Round 12: r6 (best, 24.9us) with ONE change: RSTRIDE 56 -> 52 dwords.
//  - 52 dwords = 208 B = exactly 13 float4 slots (TPB=13): zero padding
//    read per row (was 16B of pad), -7% DS bytes on the dominant DS term.
//  - Bank spread: gcd(52,32)=4 -> 8 bank-start classes (stride 56 had
//    gcd=8 -> only 4); expect conflict cycles ~halved.
//  - Everything else byte-identical to r6: lenbuf LDS staging, next-pass
//    chars int4 prefetch, 16-level branch tree (exec-masked lanes pay no
//    bank bandwidth), contiguous 512-bag chunks, coalesced float2 stores.
// Accounting (r6): HBM 10us + DS 9.6us + VALU 4.5us + staging ~1us ~= 25.1
// ~= measured 24.9 -> pipes near-serial; this shaves the DS term.

constexpr int EMB     = 50;
constexpr int RSTRIDE = 52;                  // dwords per row (208 B, no pad waste)
constexpr int TBL_F   = 256 * RSTRIDE;       // 13312 floats = 53,248 B
constexpr int NBAGS   = 1024 * 256;          // 262144
constexpr int BLOCK   = 1024;
constexpr int TPB     = 13;                  // lanes per bag (13*4 = 52 exact)
constexpr int BPP     = BLOCK / TPB;         // 78 bags per pass
constexpr int CHUNK   = 512;                 // bags per block
constexpr int NPASS   = (CHUNK + BPP - 1) / BPP;  // 7 (last pass 44 bags)
constexpr int BLOCKS  = NBAGS / CHUNK;       // 512, exact

__global__ __launch_bounds__(BLOCK, 8) void embag_r12_kernel(
    const int*   __restrict__ chars,     // [NBAGS, W=16]
    const int*   __restrict__ lengths,   // [NBAGS]
    const float* __restrict__ table,     // [256, EMB]
    float*       __restrict__ out)       // [NBAGS, EMB]
{
    __shared__ float tbl[TBL_F];
    __shared__ int   lenbuf[CHUNK];
    __shared__ float invl[17];

    const int base = blockIdx.x * CHUNK;

    // Stage table into 52-dword rows (cols 50,51 zero).
    for (int i = threadIdx.x; i < TBL_F; i += BLOCK) {
        const int r = i / RSTRIDE;
        const int c = i - r * RSTRIDE;
        tbl[i] = (c < EMB) ? table[r * EMB + c] : 0.0f;
    }
    // Stage this block's 512 lengths (coalesced int4 x 128).
    if (threadIdx.x < CHUNK / 4)
        reinterpret_cast<int4*>(lenbuf)[threadIdx.x] =
            reinterpret_cast<const int4*>(lengths + base)[threadIdx.x];
    if (threadIdx.x < 17)
        invl[threadIdx.x] = threadIdx.x ? 1.0f / (float)threadIdx.x : 0.0f;
    __syncthreads();

    const int  lb     = threadIdx.x / TPB;             // bag slot in pass
    const int  t      = threadIdx.x - lb * TPB;        // float4 slot in row
    const bool active = (lb < BPP);
    const float* rowp = tbl + 4 * t;

    // Prologue: prefetch pass-0 chars (clamped; inactive lanes load bag 0).
    int idx = active ? lb : 0;
    const int4* cp = reinterpret_cast<const int4*>(chars + (size_t)(base + idx) * 16);
    int4 c0 = cp[0], c1 = cp[1], c2 = cp[2], c3 = cp[3];

    for (int p = 0; p < NPASS; ++p) {
        // Issue next pass's chars loads NOW; they retire during the gathers.
        const int idxn = (idx + BPP < CHUNK) ? idx + BPP : CHUNK - 1;
        const int4* cpn =
            reinterpret_cast<const int4*>(chars + (size_t)(base + idxn) * 16);
        const int4 n0 = cpn[0], n1 = cpn[1], n2 = cpn[2], n3 = cpn[3];

        if (active && idx < CHUNK) {
            const int len = lenbuf[idx];                // LDS, ~free

            float4 acc = make_float4(0.f, 0.f, 0.f, 0.f);

            #define G(comp)                                                        \
                {                                                                  \
                    const float4 v =                                               \
                        *reinterpret_cast<const float4*>(rowp + (comp) * RSTRIDE); \
                    acc.x += v.x; acc.y += v.y; acc.z += v.z; acc.w += v.w;        \
                }
            G(c0.x)
            if (len > 1)  { G(c0.y)
            if (len > 2)  { G(c0.z)
            if (len > 3)  { G(c0.w)
            if (len > 4)  { G(c1.x)
            if (len > 5)  { G(c1.y)
            if (len > 6)  { G(c1.z)
            if (len > 7)  { G(c1.w)
            if (len > 8)  { G(c2.x)
            if (len > 9)  { G(c2.y)
            if (len > 10) { G(c2.z)
            if (len > 11) { G(c2.w)
            if (len > 12) { G(c3.x)
            if (len > 13) { G(c3.y)
            if (len > 14) { G(c3.z)
            if (len > 15) { G(c3.w) }}}}}}}}}}}}}}}
            #undef G

            const float inv = invl[len];
            float* ob = out + (size_t)(base + idx) * EMB + 4u * (unsigned)t;
            reinterpret_cast<float2*>(ob)[0] = make_float2(acc.x * inv, acc.y * inv);
            if (t < 12)
                reinterpret_cast<float2*>(ob)[1] = make_float2(acc.z * inv, acc.w * inv);
        }

        c0 = n0; c1 = n1; c2 = n2; c3 = n3;
        idx += BPP;
    }
}

extern "C" void kernel_launch(void* const* d_in, const int* in_sizes, int n_in,
                              void* d_out, int out_size, void* d_ws, size_t ws_size,
                              hipStream_t stream) {
    const int*   chars   = (const int*)d_in[0];   // [B,S,W] int32
    const int*   lengths = (const int*)d_in[1];   // [B,S]   int32
    const float* table   = (const float*)d_in[2]; // [256,50] f32
    float*       out     = (float*)d_out;         // [B,S,50] f32

    embag_r12_kernel<<<dim3(BLOCKS), dim3(BLOCK), 0, stream>>>(
        chars, lengths, table, out);
}